// Round 2
// baseline (461.552 us; speedup 1.0000x reference)
//
#include <hip/hip_runtime.h>

// SparseLinearAttention: B=1, L=4096, H=16, D=64, BLKQ=BLKK=64, M=N=64, T=8.
// All inputs/outputs are fp32 (per reference dtypes). Compute fp32.

#define NH   16
#define DH   64
#define NBLK 64
#define TSEL 8

// ---------------- K1: block means of q and k -> qm,km (fp32, [h][blk][d]) ----
__global__ __launch_bounds__(64) void means_kernel(const float* __restrict__ q,
                                                   const float* __restrict__ k,
                                                   float* __restrict__ qm,
                                                   float* __restrict__ km) {
  int m = blockIdx.x, h = blockIdx.y;
  const float* src = blockIdx.z ? k : q;
  float* dst = blockIdx.z ? km : qm;
  int d = threadIdx.x;
  float s = 0.f;
  for (int i = 0; i < 64; i++)
    s += src[((size_t)(m * 64 + i) * NH + h) * DH + d];
  dst[(h * NBLK + m) * DH + d] = s * (1.0f / 64.0f);
}

// ---------------- K2: block scores + top-8 per (h,m) -> lut -----------------
__global__ __launch_bounds__(64) void topk_kernel(const float* __restrict__ qm,
                                                  const float* __restrict__ km,
                                                  int* __restrict__ lut) {
  int m = blockIdx.x, h = blockIdx.y;
  int n = threadIdx.x;
  const float* qr = qm + (h * NBLK + m) * DH;
  const float* kr = km + (h * NBLK + n) * DH;
  float s = 0.f;
#pragma unroll
  for (int d = 0; d < 64; d += 4) {
    float4 a = *(const float4*)(qr + d);
    float4 b = *(const float4*)(kr + d);
    s += a.x * b.x + a.y * b.y + a.z * b.z + a.w * b.w;
  }
  float my = s;
  for (int t = 0; t < TSEL; t++) {
    float v = my; int idx = n;
#pragma unroll
    for (int off = 1; off < 64; off <<= 1) {
      float ov = __shfl_xor(v, off);
      int oi = __shfl_xor(idx, off);
      if (ov > v || (ov == v && oi < idx)) { v = ov; idx = oi; }
    }
    if (n == 0) lut[(h * NBLK + m) * TSEL + t] = idx;
    if (n == idx) my = -INFINITY;   // exclude winner; same SET as lax.top_k
  }
}

// ---------------- K3: block-sparse attention, online softmax ----------------
// grid (64, 16), 256 threads. Thread (rg,cg) owns a 4x4 register tile.
__global__ __launch_bounds__(256) void sparse_attn_kernel(const float* __restrict__ q,
                                                          const float* __restrict__ k,
                                                          const float* __restrict__ v,
                                                          const int* __restrict__ lut,
                                                          float* __restrict__ out) {
  __shared__ float q_s[64 * 64];    // [d][r]  (transposed), stride 64 (float4-aligned reads)
  __shared__ float kp_s[64 * 65];   // phase A: K [d][c] stride 64; phase B: P [r][(c+r)&63] stride 65
  __shared__ float v_s[64 * 65];    // [c][e] stride 65
  int m = blockIdx.x, h = blockIdx.y;
  int tid = threadIdx.x;
  int rg = tid >> 4, cg = tid & 15;
  int r0 = rg * 4, c0 = cg * 4;

  { // stage Q transposed: thread covers (row, 16-col segment)
    int row = tid >> 2, seg = tid & 3;
    const float* qp = q + ((size_t)(m * 64 + row) * NH + h) * DH + seg * 16;
    float f[16];
#pragma unroll
    for (int c4 = 0; c4 < 4; c4++) {
      float4 a = *(const float4*)(qp + c4 * 4);
      f[c4 * 4 + 0] = a.x; f[c4 * 4 + 1] = a.y; f[c4 * 4 + 2] = a.z; f[c4 * 4 + 3] = a.w;
    }
#pragma unroll
    for (int j = 0; j < 16; j++) q_s[(seg * 16 + j) * 64 + row] = f[j];
  }

  float accO[4][4] = {{0.f,0.f,0.f,0.f},{0.f,0.f,0.f,0.f},{0.f,0.f,0.f,0.f},{0.f,0.f,0.f,0.f}};
  float mrow[4], lrow[4];
#pragma unroll
  for (int i = 0; i < 4; i++) { mrow[i] = -INFINITY; lrow[i] = 0.f; }
  const int lut_base = (h * NBLK + m) * TSEL;

  for (int t = 0; t < TSEL; t++) {
    int blk = lut[lut_base + t];
    __syncthreads();   // previous iter's PV reads done before restaging
    { // stage K (transposed, stride 64) and V (natural, stride 65)
      int row = tid >> 2, seg = tid & 3;
      const float* kp = k + ((size_t)(blk * 64 + row) * NH + h) * DH + seg * 16;
      float f[16];
#pragma unroll
      for (int c4 = 0; c4 < 4; c4++) {
        float4 a = *(const float4*)(kp + c4 * 4);
        f[c4 * 4 + 0] = a.x; f[c4 * 4 + 1] = a.y; f[c4 * 4 + 2] = a.z; f[c4 * 4 + 3] = a.w;
      }
#pragma unroll
      for (int j = 0; j < 16; j++) kp_s[(seg * 16 + j) * 64 + row] = f[j];
      const float* vp = v + ((size_t)(blk * 64 + row) * NH + h) * DH + seg * 16;
#pragma unroll
      for (int c4 = 0; c4 < 4; c4++) {
        float4 a = *(const float4*)(vp + c4 * 4);
        f[c4 * 4 + 0] = a.x; f[c4 * 4 + 1] = a.y; f[c4 * 4 + 2] = a.z; f[c4 * 4 + 3] = a.w;
      }
#pragma unroll
      for (int j = 0; j < 16; j++) v_s[row * 65 + seg * 16 + j] = f[j];
    }
    __syncthreads();

    // S tile 4x4 (raw, unscaled)
    float s[4][4] = {{0.f,0.f,0.f,0.f},{0.f,0.f,0.f,0.f},{0.f,0.f,0.f,0.f},{0.f,0.f,0.f,0.f}};
#pragma unroll 8
    for (int d = 0; d < 64; d++) {
      float4 qv = *(const float4*)&q_s[d * 64 + r0];
      float4 kv = *(const float4*)&kp_s[d * 64 + c0];
      float qq[4] = {qv.x, qv.y, qv.z, qv.w};
      float kk[4] = {kv.x, kv.y, kv.z, kv.w};
#pragma unroll
      for (int i = 0; i < 4; i++)
#pragma unroll
        for (int j = 0; j < 4; j++)
          s[i][j] = fmaf(qq[i], kk[j], s[i][j]);
    }
    __syncthreads();   // all reads of K done before P overwrites kp_s

    float alpha[4];
#pragma unroll
    for (int i = 0; i < 4; i++) {
      float mx = fmaxf(fmaxf(s[i][0], s[i][1]), fmaxf(s[i][2], s[i][3]));
#pragma unroll
      for (int off = 1; off < 16; off <<= 1) mx = fmaxf(mx, __shfl_xor(mx, off));
      mx *= 0.125f;   // scale = D^-0.5
      float mnew = fmaxf(mrow[i], mx);
      alpha[i] = __expf(mrow[i] - mnew);
      float rs = 0.f;
      float p[4];
#pragma unroll
      for (int j = 0; j < 4; j++) {
        p[j] = __expf(fmaf(s[i][j], 0.125f, -mnew));
        rs += p[j];
      }
#pragma unroll
      for (int off = 1; off < 16; off <<= 1) rs += __shfl_xor(rs, off);
      lrow[i] = lrow[i] * alpha[i] + rs;
      mrow[i] = mnew;
      int r = r0 + i;
#pragma unroll
      for (int j = 0; j < 4; j++) {
        int c = c0 + j;
        kp_s[r * 65 + ((c + r) & 63)] = p[j];   // swizzled store, 2-way banks (free)
      }
    }
#pragma unroll
    for (int i = 0; i < 4; i++)
#pragma unroll
      for (int j = 0; j < 4; j++) accO[i][j] *= alpha[i];
    __syncthreads();   // P visible to all

    // PV: accO[i][j] += sum_c P[r0+i][c] * V[c][c0+j]
#pragma unroll 4
    for (int c = 0; c < 64; c++) {
      float pp[4], vv[4];
#pragma unroll
      for (int i = 0; i < 4; i++) {
        int r = r0 + i;
        pp[i] = kp_s[r * 65 + ((c + r) & 63)];  // 16 addrs x4 same-addr broadcast
      }
#pragma unroll
      for (int j = 0; j < 4; j++) vv[j] = v_s[c * 65 + c0 + j];
#pragma unroll
      for (int i = 0; i < 4; i++)
#pragma unroll
        for (int j = 0; j < 4; j++)
          accO[i][j] = fmaf(pp[i], vv[j], accO[i][j]);
    }
  }

  // epilogue: O /= l, fp32 store
#pragma unroll
  for (int i = 0; i < 4; i++) {
    float inv = 1.0f / lrow[i];
    int r = r0 + i;
    float* op = out + ((size_t)(m * 64 + r) * NH + h) * DH + c0;
    float4 o;
    o.x = accO[i][0] * inv; o.y = accO[i][1] * inv;
    o.z = accO[i][2] * inv; o.w = accO[i][3] * inv;
    *(float4*)op = o;
  }
}

// ---------------- K4: kvsum (H,D,D) and ksum (H,D) from k_fm, v -------------
// grid (16 splits, 16 heads), 256 threads (4 waves). Each wave owns 64 rows.
__global__ __launch_bounds__(256) void kvsum_kernel(const float* __restrict__ k,
                                                    const float* __restrict__ v,
                                                    float* __restrict__ kvsum,
                                                    float* __restrict__ ksum) {
  __shared__ float red[64 * 65];
  int h = blockIdx.y;
  int w = threadIdx.x >> 6, lane = threadIdx.x & 63;
  int base = blockIdx.x * 256 + w * 64;
  float acc[64];
#pragma unroll
  for (int e = 0; e < 64; e++) acc[e] = 0.f;
  float ksacc = 0.f;

  for (int i = 0; i < 64; i++) {
    int l = base + i;
    const size_t roff = ((size_t)l * NH + h) * DH;
    float kv = k[roff + lane];
    float mx = kv;
#pragma unroll
    for (int off = 32; off >= 1; off >>= 1) mx = fmaxf(mx, __shfl_xor(mx, off));
    float e = __expf(kv - mx);
    float sum = e;
#pragma unroll
    for (int off = 32; off >= 1; off >>= 1) sum += __shfl_xor(sum, off);
    float kfm = e / sum;              // k_fm[l][lane]
    ksacc += kfm;
    float vv = v[roff + lane];
#pragma unroll
    for (int e0 = 0; e0 < 64; e0++)
      acc[e0] = fmaf(kfm, __shfl(vv, e0), acc[e0]);
  }

  // block reduce via LDS (stride 65), wave phases
  for (int ww = 0; ww < 4; ww++) {
    if (w == ww) {
      if (ww == 0) {
#pragma unroll
        for (int e0 = 0; e0 < 64; e0++) red[lane * 65 + e0] = acc[e0];
      } else {
#pragma unroll
        for (int e0 = 0; e0 < 64; e0++) red[lane * 65 + e0] += acc[e0];
      }
    }
    __syncthreads();
  }
#pragma unroll
  for (int j = 0; j < 16; j++) {
    int idx = threadIdx.x * 16 + j;
    atomicAdd(&kvsum[h * 4096 + idx], red[(idx >> 6) * 65 + (idx & 63)]);
  }
  atomicAdd(&ksum[h * 64 + lane], ksacc);
}

// ---------------- K5: M2 = kvsum @ W^T per head -----------------------------
__global__ __launch_bounds__(256) void m2_kernel(const float* __restrict__ kvsum,
                                                 const float* __restrict__ w,
                                                 float* __restrict__ m2) {
  __shared__ float kv_s[64 * 65];
  __shared__ float w_s[64 * 65];
  int h = blockIdx.x, tid = threadIdx.x;
#pragma unroll
  for (int jj = 0; jj < 16; jj++) {
    int idx = tid * 16 + jj;
    kv_s[(idx >> 6) * 65 + (idx & 63)] = kvsum[h * 4096 + idx];
    w_s[(idx >> 6) * 65 + (idx & 63)] = w[idx];
  }
  __syncthreads();
  int d = tid >> 2, e0 = (tid & 3) * 16;
  float acc[16];
#pragma unroll
  for (int e = 0; e < 16; e++) acc[e] = 0.f;
  for (int j = 0; j < 64; j++) {
    float kvj = kv_s[d * 65 + j];
#pragma unroll
    for (int e = 0; e < 16; e++)
      acc[e] = fmaf(kvj, w_s[(e0 + e) * 65 + j], acc[e]);
  }
#pragma unroll
  for (int e = 0; e < 16; e++) m2[h * 4096 + d * 64 + e0 + e] = acc[e];
}

// ---------------- K6: linear attention output, out += o_l ------------------
// grid (64 chunks, 16 heads), 64 threads; one thread per sequence row.
__global__ __launch_bounds__(64) void linear_out_kernel(const float* __restrict__ q,
                                                        const float* __restrict__ m2,
                                                        const float* __restrict__ ksum,
                                                        const float* __restrict__ bproj,
                                                        float* __restrict__ out) {
  __shared__ float m2_s[64 * 64];   // [d][e]
  __shared__ float ks_s[64];
  __shared__ float b_s[64];
  __shared__ float er_s[64 * 64];   // [d][row-in-block] = exp(q - rowmax)
  int h = blockIdx.y, tid = threadIdx.x;
  int l = blockIdx.x * 64 + tid;
  for (int jj = 0; jj < 64; jj++)
    m2_s[jj * 64 + tid] = m2[h * 4096 + jj * 64 + tid];
  ks_s[tid] = ksum[h * 64 + tid];
  b_s[tid] = bproj[tid];
  __syncthreads();

  const float* qp = q + ((size_t)l * NH + h) * DH;
  float qv[64];
#pragma unroll
  for (int c4 = 0; c4 < 16; c4++) {
    float4 a = *(const float4*)(qp + c4 * 4);
    qv[c4 * 4 + 0] = a.x; qv[c4 * 4 + 1] = a.y; qv[c4 * 4 + 2] = a.z; qv[c4 * 4 + 3] = a.w;
  }
  float mx = -INFINITY;
#pragma unroll
  for (int j = 0; j < 64; j++) mx = fmaxf(mx, qv[j]);
  float sum = 0.f, eks = 0.f;
#pragma unroll
  for (int j = 0; j < 64; j++) {
    float e = __expf(qv[j] - mx);
    sum += e;
    eks += e * ks_s[j];
    er_s[j * 64 + tid] = e;
  }
  float inv = 1.0f / sum;
  float den = fmaf(inv, eks, 1e-6f);
  float scale = inv / den;
  __syncthreads();   // er_s of this block's threads all written (self-only read, but cheap)

  float acc[64];
#pragma unroll
  for (int e = 0; e < 64; e++) acc[e] = 0.f;
  for (int d = 0; d < 64; d++) {
    float qf = er_s[d * 64 + tid];
    const float* mrow = &m2_s[d * 64];
#pragma unroll
    for (int e4 = 0; e4 < 64; e4 += 4) {
      float4 mv = *(const float4*)(mrow + e4);   // uniform address: LDS broadcast
      acc[e4 + 0] = fmaf(qf, mv.x, acc[e4 + 0]);
      acc[e4 + 1] = fmaf(qf, mv.y, acc[e4 + 1]);
      acc[e4 + 2] = fmaf(qf, mv.z, acc[e4 + 2]);
      acc[e4 + 3] = fmaf(qf, mv.w, acc[e4 + 3]);
    }
  }

  float* op = out + ((size_t)l * NH + h) * DH;
#pragma unroll
  for (int c4 = 0; c4 < 16; c4++) {
    float4 ov = *(const float4*)(op + c4 * 4);
    ov.x += acc[c4 * 4 + 0] * scale + b_s[c4 * 4 + 0];
    ov.y += acc[c4 * 4 + 1] * scale + b_s[c4 * 4 + 1];
    ov.z += acc[c4 * 4 + 2] * scale + b_s[c4 * 4 + 2];
    ov.w += acc[c4 * 4 + 3] * scale + b_s[c4 * 4 + 3];
    *(float4*)(op + c4 * 4) = ov;
  }
}

extern "C" void kernel_launch(void* const* d_in, const int* in_sizes, int n_in,
                              void* d_out, int out_size, void* d_ws, size_t ws_size,
                              hipStream_t stream) {
  const float* q = (const float*)d_in[0];
  const float* k = (const float*)d_in[1];
  const float* v = (const float*)d_in[2];
  const float* w = (const float*)d_in[3];
  const float* b = (const float*)d_in[4];
  float* out = (float*)d_out;

  // workspace layout (fp32 words): qm 64K | km 64K | lut 8K(int) | kvsum 64K | ksum 1K | m2 64K
  float* qm = (float*)d_ws;
  float* km = qm + 65536;
  int* lut = (int*)(km + 65536);
  float* kvsum = (float*)(lut + 8192);
  float* ksum = kvsum + 65536;
  float* m2 = ksum + 1024;

  hipMemsetAsync(kvsum, 0, (65536 + 1024) * sizeof(float), stream);
  means_kernel<<<dim3(64, 16, 2), 64, 0, stream>>>(q, k, qm, km);
  topk_kernel<<<dim3(64, 16), 64, 0, stream>>>(qm, km, lut);
  sparse_attn_kernel<<<dim3(64, 16), 256, 0, stream>>>(q, k, v, lut, out);
  kvsum_kernel<<<dim3(16, 16), 256, 0, stream>>>(k, v, kvsum, ksum);
  m2_kernel<<<16, 256, 0, stream>>>(kvsum, w, m2);
  linear_out_kernel<<<dim3(64, 16), 64, 0, stream>>>(q, m2, ksum, b, out);
}

// Round 3
// 271.625 us; speedup vs baseline: 1.6992x; 1.6992x over previous
//
#include <hip/hip_runtime.h>

// SparseLinearAttention: B=1, L=4096, H=16, D=64, BLKQ=BLKK=64, M=N=64, T=8.
// fp32 I/O; sparse-attn + kvsum use bf16 MFMA (16x16x32), fp32 accumulate.

#define NH   16
#define DH   64
#define NBLK 64
#define TSEL 8

typedef unsigned short u16;
typedef unsigned int   u32;
typedef __attribute__((ext_vector_type(8))) short short8;  // 8 bf16 (4 VGPRs)
typedef __attribute__((ext_vector_type(4))) float f4;

#define MFMA_BF16(a, b, c) __builtin_amdgcn_mfma_f32_16x16x32_bf16(a, b, c, 0, 0, 0)

__device__ __forceinline__ u16 f2bf_rne(float f) {
  u32 u = __float_as_uint(f);
  u += 0x7fffu + ((u >> 16) & 1u);
  return (u16)(u >> 16);
}
__device__ __forceinline__ u32 pk2(float a, float b) {
  return (u32)f2bf_rne(a) | ((u32)f2bf_rne(b) << 16);
}
__device__ __forceinline__ float bf2f(u16 u) { return __uint_as_float(((u32)u) << 16); }

// Stage a 64x64 fp32 tile (global row stride 1024 floats = [l][h][d]) into
// row-major bf16 LDS with XOR block swizzle: logical 16B block j of row r is
// stored at physical block j^(r&7). Global reads permuted, LDS writes linear.
__device__ __forceinline__ void stage_tile(const float* __restrict__ gbase,
                                           u16* lds, int lane) {
#pragma unroll
  for (int c = 0; c < 8; c++) {
    int lo = c * 1024 + lane * 16;
    int r = lo >> 7;
    int j = ((lo >> 4) & 7) ^ (r & 7);
    const float* gp = gbase + (size_t)r * 1024 + j * 8;
    float4 a = *(const float4*)gp;
    float4 b = *(const float4*)(gp + 4);
    uint4 wv = make_uint4(pk2(a.x, a.y), pk2(a.z, a.w), pk2(b.x, b.y), pk2(b.z, b.w));
    *(uint4*)((char*)lds + lo) = wv;
  }
}

// Stage V (64 keys x 64 cols) transposed into vt[e][key] bf16, swizzled.
// lane = key row; scalar u16 scatter (2-way banks under swizzle).
__device__ __forceinline__ void stage_vt(const float* __restrict__ gbase,
                                         u16* vt, int lane) {
  const float* gp = gbase + (size_t)lane * 1024;
  int kb = lane >> 3, klo = lane & 7;
#pragma unroll
  for (int c4 = 0; c4 < 16; c4++) {
    float4 a = *(const float4*)(gp + c4 * 4);
    float vv[4] = {a.x, a.y, a.z, a.w};
#pragma unroll
    for (int jj = 0; jj < 4; jj++) {
      int e = c4 * 4 + jj;
      int bp = kb ^ (e & 7);
      *(u16*)((char*)vt + e * 128 + bp * 16 + klo * 2) = f2bf_rne(vv[jj]);
    }
  }
}

// Read an 8-bf16 MFMA fragment from a swizzled row-major bf16 tile.
__device__ __forceinline__ short8 frag_row(const u16* lds, int row, int jblk) {
  int bp = jblk ^ (row & 7);
  return *(const short8*)((const char*)lds + row * 128 + bp * 16);
}

// ---------------- K1: block means of q and k -> qm,km (fp32, [h][blk][d]) ----
__global__ __launch_bounds__(64) void means_kernel(const float* __restrict__ q,
                                                   const float* __restrict__ k,
                                                   float* __restrict__ qm,
                                                   float* __restrict__ km) {
  int m = blockIdx.x, h = blockIdx.y;
  const float* src = blockIdx.z ? k : q;
  float* dst = blockIdx.z ? km : qm;
  int d = threadIdx.x;
  float s = 0.f;
  for (int i = 0; i < 64; i++)
    s += src[((size_t)(m * 64 + i) * NH + h) * DH + d];
  dst[(h * NBLK + m) * DH + d] = s * (1.0f / 64.0f);
}

// ---------------- K2: block scores + top-8 per (h,m) -> lut -----------------
__global__ __launch_bounds__(64) void topk_kernel(const float* __restrict__ qm,
                                                  const float* __restrict__ km,
                                                  int* __restrict__ lut) {
  int m = blockIdx.x, h = blockIdx.y;
  int n = threadIdx.x;
  const float* qr = qm + (h * NBLK + m) * DH;
  const float* kr = km + (h * NBLK + n) * DH;
  float s = 0.f;
#pragma unroll
  for (int d = 0; d < 64; d += 4) {
    float4 a = *(const float4*)(qr + d);
    float4 b = *(const float4*)(kr + d);
    s += a.x * b.x + a.y * b.y + a.z * b.z + a.w * b.w;
  }
  float my = s;
  for (int t = 0; t < TSEL; t++) {
    float v = my; int idx = n;
#pragma unroll
    for (int off = 1; off < 64; off <<= 1) {
      float ov = __shfl_xor(v, off);
      int oi = __shfl_xor(idx, off);
      if (ov > v || (ov == v && oi < idx)) { v = ov; idx = oi; }
    }
    if (n == 0) lut[(h * NBLK + m) * TSEL + t] = idx;
    if (n == idx) my = -INFINITY;   // exclude winner; same SET as lax.top_k
  }
}

// ---------------- K3: block-sparse attention, MFMA split-T ------------------
// grid (16 h, 64 m), 128 threads = 2 waves. Each wave owns 4 of the 8
// selected key blocks (private LDS slabs, no barriers in main loop), online
// softmax per wave, 2-way flash merge at the end.
__global__ __launch_bounds__(128, 2) void sparse_attn_kernel(const float* __restrict__ q,
                                                             const float* __restrict__ k,
                                                             const float* __restrict__ v,
                                                             const int* __restrict__ lut,
                                                             float* __restrict__ out) {
  __shared__ __align__(16) char smem[40960];
  u16* q_l = (u16*)smem;                              // 8KB shared Q tile
  int h = blockIdx.x, m = blockIdx.y;
  int tid = threadIdx.x;
  int w = tid >> 6, lane = tid & 63;
  int lq = lane & 15, quad = lane >> 4;
  u16* kp_l = (u16*)(smem + 8192 + w * 8192);         // per-wave K tile, then P tile
  u16* vt_l = (u16*)(smem + 24576 + w * 8192);        // per-wave V^T tile

  { // stage Q (shared, 128 threads x 4 chunks)
#pragma unroll
    for (int c = 0; c < 4; c++) {
      int lo = c * 2048 + tid * 16;
      int r = lo >> 7;
      int j = ((lo >> 4) & 7) ^ (r & 7);
      const float* gp = q + ((size_t)(m * 64 + r) * NH + h) * DH + j * 8;
      float4 a = *(const float4*)gp;
      float4 b = *(const float4*)(gp + 4);
      *(uint4*)(smem + lo) = make_uint4(pk2(a.x, a.y), pk2(a.z, a.w),
                                        pk2(b.x, b.y), pk2(b.z, b.w));
    }
  }
  __syncthreads();

  f4 o[4][4];   // O^T frags: e = et*16+quad*4+r, q = qt*16+lq
  f4 zz = {0.f, 0.f, 0.f, 0.f};
#pragma unroll
  for (int et = 0; et < 4; et++)
#pragma unroll
    for (int qt = 0; qt < 4; qt++) o[et][qt] = zz;
  float mrun[4], lrun[4];
#pragma unroll
  for (int i = 0; i < 4; i++) { mrun[i] = -INFINITY; lrun[i] = 0.f; }

  const int lb = (h * NBLK + m) * TSEL;
  for (int it = 0; it < 4; it++) {
    int blk = lut[lb + w * 4 + it];
    const float* kb_ = k + ((size_t)(blk * 64) * NH + h) * DH;
    const float* vb_ = v + ((size_t)(blk * 64) * NH + h) * DH;
    stage_tile(kb_, kp_l, lane);
    stage_vt(vb_, vt_l, lane);

    // S^T = K·Q^T : frag (kt,qt): key = kt*16+quad*4+r, query = qt*16+lq
    f4 s[4][4];
#pragma unroll
    for (int kt = 0; kt < 4; kt++)
#pragma unroll
      for (int qt = 0; qt < 4; qt++) s[kt][qt] = zz;
#pragma unroll
    for (int ks = 0; ks < 2; ks++) {
      short8 afr[4], bfr[4];
#pragma unroll
      for (int kt = 0; kt < 4; kt++) afr[kt] = frag_row(kp_l, kt * 16 + lq, 4 * ks + quad);
#pragma unroll
      for (int qt = 0; qt < 4; qt++) bfr[qt] = frag_row(q_l, qt * 16 + lq, 4 * ks + quad);
#pragma unroll
      for (int kt = 0; kt < 4; kt++)
#pragma unroll
        for (int qt = 0; qt < 4; qt++)
          s[kt][qt] = MFMA_BF16(afr[kt], bfr[qt], s[kt][qt]);
    }

    // online softmax per query (q = qt*16+lq); write P[q][key] bf16 into kp_l
#pragma unroll
    for (int qt = 0; qt < 4; qt++) {
      float mp = -INFINITY;
#pragma unroll
      for (int kt = 0; kt < 4; kt++)
#pragma unroll
        for (int r = 0; r < 4; r++) mp = fmaxf(mp, s[kt][qt][r]);
      mp = fmaxf(mp, __shfl_xor(mp, 16));
      mp = fmaxf(mp, __shfl_xor(mp, 32));
      mp *= 0.125f;
      float mn = fmaxf(mrun[qt], mp);
      float al = __expf(mrun[qt] - mn);
      mrun[qt] = mn;
      float rs = 0.f;
      int qrow = qt * 16 + lq;
#pragma unroll
      for (int kt = 0; kt < 4; kt++)
#pragma unroll
        for (int r = 0; r < 4; r++) {
          float p = __expf(fmaf(s[kt][qt][r], 0.125f, -mn));
          rs += p;
          int key = kt * 16 + quad * 4 + r;
          int bp = (key >> 3) ^ (qrow & 7);
          *(u16*)((char*)kp_l + qrow * 128 + bp * 16 + (key & 7) * 2) =
              (u16)(__float_as_uint(p) >> 16);   // trunc-to-bf16 (p>=0)
        }
      rs += __shfl_xor(rs, 16);
      rs += __shfl_xor(rs, 32);
      lrun[qt] = lrun[qt] * al + rs;
#pragma unroll
      for (int et = 0; et < 4; et++)
#pragma unroll
        for (int r = 0; r < 4; r++) o[et][qt][r] *= al;
    }

    // O^T += Vt·P^T : A = vt rows (e), B = P rows (q)
#pragma unroll
    for (int ks = 0; ks < 2; ks++) {
      short8 av[4], bp_[4];
#pragma unroll
      for (int et = 0; et < 4; et++) av[et] = frag_row(vt_l, et * 16 + lq, 4 * ks + quad);
#pragma unroll
      for (int qt = 0; qt < 4; qt++) bp_[qt] = frag_row(kp_l, qt * 16 + lq, 4 * ks + quad);
#pragma unroll
      for (int et = 0; et < 4; et++)
#pragma unroll
        for (int qt = 0; qt < 4; qt++)
          o[et][qt] = MFMA_BF16(av[et], bp_[qt], o[et][qt]);
    }
  }

  // ---- 2-way merge ----
  float* o_acc = (float*)(smem + 8192);     // 64 x 65 fp32 (16640 B)
  float* m_l = (float*)(smem + 24832);      // [2][64]
  float* l_l = (float*)(smem + 25344);      // [2][64]
  float* l2_l = (float*)(smem + 25856);     // [2][64]
  __syncthreads();
  for (int i = tid; i < 64 * 65; i += 128) o_acc[i] = 0.f;
  if (quad == 0) {
#pragma unroll
    for (int qt = 0; qt < 4; qt++) {
      m_l[w * 64 + qt * 16 + lq] = mrun[qt];
      l_l[w * 64 + qt * 16 + lq] = lrun[qt];
    }
  }
  __syncthreads();
#pragma unroll
  for (int qt = 0; qt < 4; qt++) {
    float m0 = m_l[qt * 16 + lq], m1 = m_l[64 + qt * 16 + lq];
    float ms = fmaxf(m0, m1);
    float fac = __expf(mrun[qt] - ms);
    if (quad == 0) l2_l[w * 64 + qt * 16 + lq] = lrun[qt] * fac;
#pragma unroll
    for (int et = 0; et < 4; et++)
#pragma unroll
      for (int r = 0; r < 4; r++)
        atomicAdd(&o_acc[(qt * 16 + lq) * 65 + et * 16 + quad * 4 + r],
                  o[et][qt][r] * fac);
  }
  __syncthreads();
  { // epilogue: thread covers (q = tid>>1, half = tid&1 -> 32 cols)
    int qq = tid >> 1, half = tid & 1;
    float ls = l2_l[qq] + l2_l[64 + qq];
    float inv = 1.0f / ls;
    float* op = out + ((size_t)(m * 64 + qq) * NH + h) * DH + half * 32;
#pragma unroll
    for (int c4 = 0; c4 < 8; c4++) {
      float4 ov;
      ov.x = o_acc[qq * 65 + half * 32 + c4 * 4 + 0] * inv;
      ov.y = o_acc[qq * 65 + half * 32 + c4 * 4 + 1] * inv;
      ov.z = o_acc[qq * 65 + half * 32 + c4 * 4 + 2] * inv;
      ov.w = o_acc[qq * 65 + half * 32 + c4 * 4 + 3] * inv;
      *(float4*)(op + c4 * 4) = ov;
    }
  }
}

// ---------------- K4: kvsum partials via MFMA -------------------------------
// grid (8 splits, 16 h), 64 threads (1 wave). Each block: 8 key-chunks of 64
// rows; per chunk: row softmax (lane=row), transpose k_fm via LDS, V^T via
// LDS, MFMA accumulate 64x64. Writes fp32 partial slab (no atomics).
__global__ __launch_bounds__(64) void kvsum_kernel(const float* __restrict__ k,
                                                   const float* __restrict__ v,
                                                   float* __restrict__ kvp,
                                                   float* __restrict__ ksp) {
  __shared__ __align__(16) u16 vt[4096];
  __shared__ __align__(16) u16 kfmT[4096];
  int s = blockIdx.x, h = blockIdx.y;
  int lane = threadIdx.x;
  int lq = lane & 15, quad = lane >> 4;

  f4 acc[4][4];
  f4 zz = {0.f, 0.f, 0.f, 0.f};
#pragma unroll
  for (int dt = 0; dt < 4; dt++)
#pragma unroll
    for (int et = 0; et < 4; et++) acc[dt][et] = zz;
  float ksacc = 0.f;

  for (int n = s * 8; n < s * 8 + 8; n++) {
    const float* kb_ = k + ((size_t)(n * 64) * NH + h) * DH;
    const float* vb_ = v + ((size_t)(n * 64) * NH + h) * DH;
    stage_vt(vb_, vt, lane);

    { // row softmax over d, lane = row
      const float* kr = kb_ + (size_t)lane * 1024;
      float kv[64];
#pragma unroll
      for (int c4 = 0; c4 < 16; c4++) {
        float4 a = *(const float4*)(kr + c4 * 4);
        kv[c4 * 4] = a.x; kv[c4 * 4 + 1] = a.y; kv[c4 * 4 + 2] = a.z; kv[c4 * 4 + 3] = a.w;
      }
      float mx = -INFINITY;
#pragma unroll
      for (int d = 0; d < 64; d++) mx = fmaxf(mx, kv[d]);
      float sum = 0.f;
#pragma unroll
      for (int d = 0; d < 64; d++) { kv[d] = __expf(kv[d] - mx); sum += kv[d]; }
      float inv = 1.0f / sum;
      int rb = lane >> 3, rlo = lane & 7;
#pragma unroll
      for (int d = 0; d < 64; d++) {
        int bp = rb ^ (d & 7);
        *(u16*)((char*)kfmT + d * 128 + bp * 16 + rlo * 2) = f2bf_rne(kv[d] * inv);
      }
    }

    { // ksum partial: lane = d, sum kfmT row
      float kp0 = 0.f;
#pragma unroll
      for (int jb = 0; jb < 8; jb++) {
        short8 x = frag_row(kfmT, lane, jb);
#pragma unroll
        for (int e = 0; e < 8; e++) kp0 += bf2f((u16)x[e]);
      }
      ksacc += kp0;
    }

    // kvsum += kfm^T @ v  (A = kfmT rows (d), B = vt rows (e))
#pragma unroll
    for (int ks2 = 0; ks2 < 2; ks2++) {
      short8 a_[4], b_[4];
#pragma unroll
      for (int dt = 0; dt < 4; dt++) a_[dt] = frag_row(kfmT, dt * 16 + lq, 4 * ks2 + quad);
#pragma unroll
      for (int et = 0; et < 4; et++) b_[et] = frag_row(vt, et * 16 + lq, 4 * ks2 + quad);
#pragma unroll
      for (int dt = 0; dt < 4; dt++)
#pragma unroll
        for (int et = 0; et < 4; et++)
          acc[dt][et] = MFMA_BF16(a_[dt], b_[et], acc[dt][et]);
    }
  }

  float* kvb = kvp + ((size_t)(s * 16 + h)) * 4096;
#pragma unroll
  for (int dt = 0; dt < 4; dt++)
#pragma unroll
    for (int et = 0; et < 4; et++)
#pragma unroll
      for (int r = 0; r < 4; r++)
        kvb[(dt * 16 + quad * 4 + r) * 64 + et * 16 + lq] = acc[dt][et][r];
  ksp[(s * 16 + h) * 64 + lane] = ksacc;
}

// ---------------- K5: reduce slabs + M2 = kvsum @ W^T per head --------------
__global__ __launch_bounds__(256) void m2_kernel(const float* __restrict__ kvp,
                                                 const float* __restrict__ ksp,
                                                 const float* __restrict__ w,
                                                 float* __restrict__ m2,
                                                 float* __restrict__ ksum) {
  __shared__ float kv_s[64 * 65];
  __shared__ float w_s[64 * 65];
  int h = blockIdx.x, tid = threadIdx.x;
#pragma unroll
  for (int jj = 0; jj < 16; jj++) {
    int idx = tid * 16 + jj;
    float sv = 0.f;
    for (int s2 = 0; s2 < 8; s2++) sv += kvp[((size_t)(s2 * 16 + h)) * 4096 + idx];
    kv_s[(idx >> 6) * 65 + (idx & 63)] = sv;
    w_s[(idx >> 6) * 65 + (idx & 63)] = w[idx];
  }
  if (tid < 64) {
    float ss = 0.f;
    for (int s2 = 0; s2 < 8; s2++) ss += ksp[(s2 * 16 + h) * 64 + tid];
    ksum[h * 64 + tid] = ss;
  }
  __syncthreads();
  int d = tid >> 2, e0 = (tid & 3) * 16;
  float acc[16];
#pragma unroll
  for (int e = 0; e < 16; e++) acc[e] = 0.f;
  for (int j = 0; j < 64; j++) {
    float kvj = kv_s[d * 65 + j];
#pragma unroll
    for (int e = 0; e < 16; e++)
      acc[e] = fmaf(kvj, w_s[(e0 + e) * 65 + j], acc[e]);
  }
#pragma unroll
  for (int e = 0; e < 16; e++) m2[h * 4096 + d * 64 + e0 + e] = acc[e];
}

// ---------------- K6: linear attention output, out += o_l ------------------
__global__ __launch_bounds__(64) void linear_out_kernel(const float* __restrict__ q,
                                                        const float* __restrict__ m2,
                                                        const float* __restrict__ ksum,
                                                        const float* __restrict__ bproj,
                                                        float* __restrict__ out) {
  __shared__ float m2_s[64 * 64];
  __shared__ float ks_s[64];
  __shared__ float b_s[64];
  __shared__ float er_s[64 * 64];
  int h = blockIdx.y, tid = threadIdx.x;
  int l = blockIdx.x * 64 + tid;
  for (int jj = 0; jj < 64; jj++)
    m2_s[jj * 64 + tid] = m2[h * 4096 + jj * 64 + tid];
  ks_s[tid] = ksum[h * 64 + tid];
  b_s[tid] = bproj[tid];
  __syncthreads();

  const float* qp = q + ((size_t)l * NH + h) * DH;
  float qv[64];
#pragma unroll
  for (int c4 = 0; c4 < 16; c4++) {
    float4 a = *(const float4*)(qp + c4 * 4);
    qv[c4 * 4] = a.x; qv[c4 * 4 + 1] = a.y; qv[c4 * 4 + 2] = a.z; qv[c4 * 4 + 3] = a.w;
  }
  float mx = -INFINITY;
#pragma unroll
  for (int j = 0; j < 64; j++) mx = fmaxf(mx, qv[j]);
  float sum = 0.f, eks = 0.f;
#pragma unroll
  for (int j = 0; j < 64; j++) {
    float e = __expf(qv[j] - mx);
    sum += e;
    eks += e * ks_s[j];
    er_s[j * 64 + tid] = e;
  }
  float inv = 1.0f / sum;
  float den = fmaf(inv, eks, 1e-6f);
  float scale = inv / den;

  float acc[64];
#pragma unroll
  for (int e = 0; e < 64; e++) acc[e] = 0.f;
  for (int d = 0; d < 64; d++) {
    float qf = er_s[d * 64 + tid];
    const float* mrow = &m2_s[d * 64];
#pragma unroll
    for (int e4 = 0; e4 < 64; e4 += 4) {
      float4 mv = *(const float4*)(mrow + e4);
      acc[e4 + 0] = fmaf(qf, mv.x, acc[e4 + 0]);
      acc[e4 + 1] = fmaf(qf, mv.y, acc[e4 + 1]);
      acc[e4 + 2] = fmaf(qf, mv.z, acc[e4 + 2]);
      acc[e4 + 3] = fmaf(qf, mv.w, acc[e4 + 3]);
    }
  }

  float* op = out + ((size_t)l * NH + h) * DH;
#pragma unroll
  for (int c4 = 0; c4 < 16; c4++) {
    float4 ov = *(const float4*)(op + c4 * 4);
    ov.x += acc[c4 * 4 + 0] * scale + b_s[c4 * 4 + 0];
    ov.y += acc[c4 * 4 + 1] * scale + b_s[c4 * 4 + 1];
    ov.z += acc[c4 * 4 + 2] * scale + b_s[c4 * 4 + 2];
    ov.w += acc[c4 * 4 + 3] * scale + b_s[c4 * 4 + 3];
    *(float4*)(op + c4 * 4) = ov;
  }
}

extern "C" void kernel_launch(void* const* d_in, const int* in_sizes, int n_in,
                              void* d_out, int out_size, void* d_ws, size_t ws_size,
                              hipStream_t stream) {
  const float* q = (const float*)d_in[0];
  const float* k = (const float*)d_in[1];
  const float* v = (const float*)d_in[2];
  const float* w = (const float*)d_in[3];
  const float* b = (const float*)d_in[4];
  float* out = (float*)d_out;

  // ws (fp32 words): qm 64K | km 64K | lut 8K(int) | kvp 512K | ksp 8K | ksum 1K | m2 64K
  float* qm = (float*)d_ws;
  float* km = qm + 65536;
  int* lut = (int*)(km + 65536);
  float* kvp = (float*)(lut + 8192);
  float* ksp = kvp + 524288;
  float* ksum = ksp + 8192;
  float* m2 = ksum + 1024;

  means_kernel<<<dim3(64, 16, 2), 64, 0, stream>>>(q, k, qm, km);
  topk_kernel<<<dim3(64, 16), 64, 0, stream>>>(qm, km, lut);
  sparse_attn_kernel<<<dim3(16, 64), 128, 0, stream>>>(q, k, v, lut, out);
  kvsum_kernel<<<dim3(8, 16), 64, 0, stream>>>(k, v, kvp, ksp);
  m2_kernel<<<16, 256, 0, stream>>>(kvp, ksp, w, m2, ksum);
  linear_out_kernel<<<dim3(64, 16), 64, 0, stream>>>(q, m2, ksum, b, out);
}